// Round 3
// baseline (210.822 us; speedup 1.0000x reference)
//
#include <hip/hip_runtime.h>
#include <math.h>

// TopKRouter: logits = x(16384x2048) @ W(2048x64) + b; softmax E=64; top-2.
// Output: d_out[0:32768] = indices (as float), d_out[32768:65536] = probs.
//
// R2: E-split restructure for occupancy. Waves split experts (wave t = experts
// 16t..16t+15, full K) instead of K. x staged cooperatively: one shared 16x64
// fp32 chunk per block, double-buffered (8.7 KB LDS vs 69.6 KB). acc 8 VGPR,
// x-regs 8, W-regs 8 -> ~90-110 VGPR => 4 blocks/CU x 4 waves = 16 waves/CU
// (was 8). Barriers use raw s_barrier + lgkmcnt(0) only (no vmcnt drain) so
// x prefetch (2 chunks deep) stays in flight across barriers. Split-3 fp16
// numerics identical to R0 baseline (202.6 us).

#define D_DIM 2048
#define E_DIM 64
#define M_DIM 16384
#define RM 16             // rows per block
#define BKC 64            // k per chunk
#define NCH 32            // chunks (2048/64)
#define XSTR 68           // padded LDS row stride in uints

typedef _Float16 half8 __attribute__((ext_vector_type(8)));
typedef float floatx4 __attribute__((ext_vector_type(4)));
typedef unsigned int uint;

// ---------------- kernel 1: W split into fragment-linear layout (unchanged) ----
// For k-step g (32 k), tile t, plane p (0=hi,1=lo):
//   wsT[((g*4+t)*2+p)*512 + lane*8 + j] = plane(W[g*32 + quad*8 + j][16t + c]),
//   lane = quad*16 + c.
__global__ __launch_bounds__(256) void split_w_kernel(
    const float* __restrict__ Wm, _Float16* __restrict__ wsT)
{
    const int tid = threadIdx.x;
    const int n   = tid & 63;
    const int kk0 = tid >> 6;           // 0..3
    const int g   = blockIdx.x;         // 0..63
    #pragma unroll
    for (int r = 0; r < 8; r++) {
        const int kk = kk0 + r * 4;     // 0..31
        const float v = Wm[(size_t)(g * 32 + kk) * E_DIM + n];
        const _Float16 h = (_Float16)v;
        const _Float16 l = (_Float16)((v - (float)h) * 2048.0f);
        const int t = n >> 4, cc = n & 15, qd = kk >> 3, j = kk & 7;
        const size_t base = (size_t)((g * 4 + t) * 2) * 512 + (size_t)(qd * 16 + cc) * 8 + j;
        wsT[base]       = h;
        wsT[base + 512] = l;
    }
}

// ---------------- kernel 2: cooperative-stage MFMA GEMM + softmax + top-2 ------
__global__ __launch_bounds__(256, 4) void router_mfma_kernel(
    const float* __restrict__ x, const _Float16* __restrict__ wsT,
    const float* __restrict__ bias, float* __restrict__ out)
{
    __shared__ uint xbuf[2][RM * XSTR];   // 2 x 16 x 68 x 4 B = 8704 B

    const int tid  = threadIdx.x;
    const int lane = tid & 63;
    const int wave = tid >> 6;            // = expert tile t (0..3)
    const int c    = lane & 15;
    const int quad = lane >> 4;
    const int rs   = tid >> 4;            // staging row 0..15
    const int c4   = tid & 15;            // staging k-quad 0..15
    const int r0   = blockIdx.x * RM;

    // staging: thread (rs,c4) loads x[r0+rs][chunk*64 + c4*4 .. +3]
    const float*    xg = x   + (size_t)(r0 + rs) * D_DIM + c4 * 4;
    // W frags for tile t=wave: wsT[g*4096 + wave*1024 + plane*512 + lane*8 + j]
    const _Float16* wt = wsT + (size_t)wave * 1024 + (size_t)lane * 8;

    floatx4 accm = {0.f, 0.f, 0.f, 0.f};
    floatx4 accl = {0.f, 0.f, 0.f, 0.f};
    float4 ra, rb;

    auto xload = [&](int n) -> float4 {
        const int nn = n < NCH ? n : NCH - 1;   // clamp (redundant L2-hit loads)
        return *reinterpret_cast<const float4*>(xg + nn * BKC);
    };
    auto stage = [&](int buf, const float4& v4) {
        const float v[4] = {v4.x, v4.y, v4.z, v4.w};
        uint p[4];
        #pragma unroll
        for (int q = 0; q < 4; q++) {
            const _Float16 h = (_Float16)v[q];
            const _Float16 l = (_Float16)((v[q] - (float)h) * 2048.0f);
            p[q] = (uint)__builtin_bit_cast(unsigned short, h)
                 | ((uint)__builtin_bit_cast(unsigned short, l) << 16);
        }
        *reinterpret_cast<uint4*>(&xbuf[buf][rs * XSTR + c4 * 4]) =
            make_uint4(p[0], p[1], p[2], p[3]);
    };
    auto compute = [&](int buf, int n) {
        #pragma unroll
        for (int s = 0; s < 2; s++) {
            const _Float16* wp = wt + (size_t)(2 * n + s) * 4096;
            const half8 wh = *reinterpret_cast<const half8*>(wp);
            const half8 wl = *reinterpret_cast<const half8*>(wp + 512);
            const uint* rp = &xbuf[buf][c * XSTR + s * 32 + quad * 8];
            uint u8[8];
            *reinterpret_cast<uint4*>(u8)     = *reinterpret_cast<const uint4*>(rp);
            *reinterpret_cast<uint4*>(u8 + 4) = *reinterpret_cast<const uint4*>(rp + 4);
            uint hh[4], ll[4];
            #pragma unroll
            for (int q = 0; q < 4; q++) {
                hh[q] = (u8[2 * q] & 0xffffu) | (u8[2 * q + 1] << 16);
                ll[q] = (u8[2 * q] >> 16) | (u8[2 * q + 1] & 0xffff0000u);
            }
            const half8 ah = __builtin_bit_cast(half8, make_uint4(hh[0], hh[1], hh[2], hh[3]));
            const half8 al = __builtin_bit_cast(half8, make_uint4(ll[0], ll[1], ll[2], ll[3]));
            accm = __builtin_amdgcn_mfma_f32_16x16x32_f16(ah, wh, accm, 0, 0, 0);
            accl = __builtin_amdgcn_mfma_f32_16x16x32_f16(al, wh, accl, 0, 0, 0);
            accl = __builtin_amdgcn_mfma_f32_16x16x32_f16(ah, wl, accl, 0, 0, 0);
        }
    };
    // LDS-publish barrier WITHOUT vmcnt drain: global x prefetches stay in
    // flight across it (ds_writes are complete per lgkmcnt(0); readers wait
    // on the other side of s_barrier). m201-verified pattern.
    auto barrier_lds = [&]() {
        asm volatile("s_waitcnt lgkmcnt(0)" ::: "memory");
        __builtin_amdgcn_s_barrier();
        asm volatile("" ::: "memory");
    };

    // prologue: buf0 <- chunk0; rb = chunk1; ra = chunk2 (in flight)
    ra = xload(0);
    rb = xload(1);
    stage(0, ra);
    ra = xload(2);

    #pragma unroll 1
    for (int n = 0; n < NCH; n += 2) {
        barrier_lds();                    // buf0 (chunk n) published
        compute(0, n);
        stage(1, rb);                     // chunk n+1 -> buf1 (disjoint from buf0 readers)
        rb = xload(n + 3);
        barrier_lds();                    // buf1 (chunk n+1) published
        compute(1, n + 1);
        if (n + 2 < NCH) stage(0, ra);    // chunk n+2 -> buf0
        ra = xload(n + 4);
    }

    // ---- epilogue: gather 16x64 logits, softmax, top-2 (wave 0) ----
    __syncthreads();
    float* red = reinterpret_cast<float*>(&xbuf[0][0]);   // red[row*65 + expert]
    const float scale = 1.0f / 2048.0f;
    #pragma unroll
    for (int i = 0; i < 4; i++)
        red[(quad * 4 + i) * 65 + wave * 16 + c] = accm[i] + accl[i] * scale;
    __syncthreads();

    if (wave != 0) return;

    float bvt[4];
    #pragma unroll
    for (int t = 0; t < 4; t++) bvt[t] = bias[c + 16 * t];

    #pragma unroll
    for (int i = 0; i < 4; i++) {
        const int row = quad * 4 + i;
        float lt[4];
        #pragma unroll
        for (int t = 0; t < 4; t++)
            lt[t] = red[row * 65 + 16 * t + c] + bvt[t];
        const float l0 = lt[0], l1 = lt[1], l2 = lt[2], l3 = lt[3];

        float m = fmaxf(fmaxf(l0, l1), fmaxf(l2, l3));
        #pragma unroll
        for (int off = 1; off < 16; off <<= 1)
            m = fmaxf(m, __shfl_xor(m, off, 64));

        const float e0 = expf(l0 - m), e1 = expf(l1 - m);
        const float e2 = expf(l2 - m), e3 = expf(l3 - m);
        float s = e0 + e1 + e2 + e3;
        #pragma unroll
        for (int off = 1; off < 16; off <<= 1)
            s += __shfl_xor(s, off, 64);

        const float p0 = e0 / s, p1 = e1 / s, p2 = e2 / s, p3 = e3 / s;

        // keys: (prob bits << 32) | (63 - expert); experts c, c+16, c+32, c+48
        const unsigned long long ka =
            ((unsigned long long)__float_as_uint(p0) << 32) | (unsigned long long)(63 - c);
        const unsigned long long kb_ =
            ((unsigned long long)__float_as_uint(p1) << 32) | (unsigned long long)(47 - c);
        const unsigned long long kc_ =
            ((unsigned long long)__float_as_uint(p2) << 32) | (unsigned long long)(31 - c);
        const unsigned long long kd =
            ((unsigned long long)__float_as_uint(p3) << 32) | (unsigned long long)(15 - c);

        unsigned long long hi1 = ka > kb_ ? ka : kb_, lo1 = ka > kb_ ? kb_ : ka;
        unsigned long long hi2 = kc_ > kd ? kc_ : kd, lo2 = kc_ > kd ? kd : kc_;
        unsigned long long k1 = hi1 > hi2 ? hi1 : hi2;
        unsigned long long mn = hi1 > hi2 ? hi2 : hi1;
        unsigned long long mx = lo1 > lo2 ? lo1 : lo2;
        unsigned long long k2 = mn > mx ? mn : mx;

        #pragma unroll
        for (int off = 1; off < 16; off <<= 1) {
            const unsigned long long o1 = __shfl_xor(k1, off, 64);
            const unsigned long long o2 = __shfl_xor(k2, off, 64);
            const unsigned long long n1 = k1 > o1 ? k1 : o1;
            const unsigned long long w1 = k1 > o1 ? o1 : k1;   // loser of firsts
            const unsigned long long w2 = k2 > o2 ? k2 : o2;   // best of seconds
            k1 = n1;
            k2 = w1 > w2 ? w1 : w2;
        }

        if (c == 0) {
            const int gr = r0 + row;
            out[gr * 2 + 0] = (float)(63 - (int)(k1 & 0xFFFFFFFFull));
            out[gr * 2 + 1] = (float)(63 - (int)(k2 & 0xFFFFFFFFull));
            out[M_DIM * 2 + gr * 2 + 0] = __uint_as_float((unsigned)(k1 >> 32));
            out[M_DIM * 2 + gr * 2 + 1] = __uint_as_float((unsigned)(k2 >> 32));
        }
    }
}

extern "C" void kernel_launch(void* const* d_in, const int* in_sizes, int n_in,
                              void* d_out, int out_size, void* d_ws, size_t ws_size,
                              hipStream_t stream) {
    const float* x  = (const float*)d_in[0];
    const float* Wm = (const float*)d_in[1];
    const float* b  = (const float*)d_in[2];
    float* out = (float*)d_out;
    _Float16* wsT = (_Float16*)d_ws;   // 64*4*2*512*2 B = 512 KB

    split_w_kernel<<<dim3(64), dim3(256), 0, stream>>>(Wm, wsT);
    router_mfma_kernel<<<dim3(M_DIM / RM), dim3(256), 0, stream>>>(x, wsT, b, out);
}

// Round 5
// 209.757 us; speedup vs baseline: 1.0051x; 1.0051x over previous
//
#include <hip/hip_runtime.h>
#include <math.h>

// TopKRouter: logits = x(16384x2048) @ W(2048x64) + b; softmax E=64; top-2.
// Output: d_out[0:32768] = indices (as float), d_out[32768:65536] = probs.
//
// R4: RM=32 / 512-thread / 8-wave geometry. Wave = (tau = row-half) x (et =
// expert tile); every wave computes on every cooperatively-staged chunk.
// Fixes vs R3 (210.8 us): (a) W L2 traffic halved 512->256 MB (RM 16->32);
// (b) W frags register-prefetched one barrier EARLY (WA/WB) so L2 latency
// hides under previous chunk's MFMAs (R3 loaded W after the barrier's asm
// clobber -> exposed ~200cyc/chunk); (c) x prefetch deepened to 4 chunks
// (named q0..q3, static indices) to cover ~900cyc HBM latency.
// Barriers remain lgkmcnt-only (no vmcnt drain) so all prefetches stay in
// flight across them. Split-3 fp16 numerics bit-identical to R0/R3.
// R4b: identical resubmission — R4 bench failed at GPU acquisition.

#define D_DIM 2048
#define E_DIM 64
#define M_DIM 16384
#define RM 32             // rows per block
#define BKC 64            // k per chunk
#define NCH 32            // chunks (2048/64)
#define XSTR 68           // padded LDS row stride in uints

typedef _Float16 half8 __attribute__((ext_vector_type(8)));
typedef float floatx4 __attribute__((ext_vector_type(4)));
typedef unsigned int uint;

// ---------------- kernel 1: W split into fragment-linear layout (unchanged) ----
// For k-step g (32 k), tile t, plane p (0=hi,1=lo):
//   wsT[((g*4+t)*2+p)*512 + lane*8 + j] = plane(W[g*32 + quad*8 + j][16t + c]),
//   lane = quad*16 + c.
__global__ __launch_bounds__(256) void split_w_kernel(
    const float* __restrict__ Wm, _Float16* __restrict__ wsT)
{
    const int tid = threadIdx.x;
    const int n   = tid & 63;
    const int kk0 = tid >> 6;           // 0..3
    const int g   = blockIdx.x;         // 0..63
    #pragma unroll
    for (int r = 0; r < 8; r++) {
        const int kk = kk0 + r * 4;     // 0..31
        const float v = Wm[(size_t)(g * 32 + kk) * E_DIM + n];
        const _Float16 h = (_Float16)v;
        const _Float16 l = (_Float16)((v - (float)h) * 2048.0f);
        const int t = n >> 4, cc = n & 15, qd = kk >> 3, j = kk & 7;
        const size_t base = (size_t)((g * 4 + t) * 2) * 512 + (size_t)(qd * 16 + cc) * 8 + j;
        wsT[base]       = h;
        wsT[base + 512] = l;
    }
}

// ---------------- kernel 2: cooperative-stage MFMA GEMM + softmax + top-2 ------
__global__ __launch_bounds__(512, 4) void router_mfma_kernel(
    const float* __restrict__ x, const _Float16* __restrict__ wsT,
    const float* __restrict__ bias, float* __restrict__ out)
{
    __shared__ uint xbuf[2][RM * XSTR];   // 2 x 32 x 68 x 4 B = 17408 B

    const int tid  = threadIdx.x;         // 0..511
    const int lane = tid & 63;
    const int wave = tid >> 6;            // 0..7
    const int et   = wave & 3;            // expert tile (16 experts)
    const int tau  = wave >> 2;           // row half (16 rows)
    const int c    = lane & 15;
    const int quad = lane >> 4;
    const int rs   = tid >> 4;            // staging row 0..31
    const int c4   = tid & 15;            // staging k-quad 0..15
    const int r0   = blockIdx.x * RM;

    // staging: thread (rs,c4) loads x[r0+rs][chunk*64 + c4*4 .. +3]
    const float*    xg = x   + (size_t)(r0 + rs) * D_DIM + c4 * 4;
    // W frags for tile et: wsT[g*4096 + et*1024 + plane*512 + lane*8 + j]
    const _Float16* wt = wsT + (size_t)et * 1024 + (size_t)lane * 8;

    floatx4 accm = {0.f, 0.f, 0.f, 0.f};
    floatx4 accl = {0.f, 0.f, 0.f, 0.f};

    auto xload = [&](int n) -> float4 {
        const int nn = n < NCH ? n : NCH - 1;   // clamp (redundant L2-hit loads)
        return *reinterpret_cast<const float4*>(xg + nn * BKC);
    };
    // W for chunk m: wv = {wh(s=0), wl(s=0), wh(s=1), wl(s=1)}
    auto loadWc = [&](int m, half8* wv) {
        const int mm = m < NCH ? m : NCH - 1;
        const _Float16* p0 = wt + (size_t)(2 * mm) * 4096;
        wv[0] = *reinterpret_cast<const half8*>(p0);
        wv[1] = *reinterpret_cast<const half8*>(p0 + 512);
        wv[2] = *reinterpret_cast<const half8*>(p0 + 4096);
        wv[3] = *reinterpret_cast<const half8*>(p0 + 4096 + 512);
    };
    auto stage = [&](int buf, const float4& v4) {
        const float v[4] = {v4.x, v4.y, v4.z, v4.w};
        uint p[4];
        #pragma unroll
        for (int q = 0; q < 4; q++) {
            const _Float16 h = (_Float16)v[q];
            const _Float16 l = (_Float16)((v[q] - (float)h) * 2048.0f);
            p[q] = (uint)__builtin_bit_cast(unsigned short, h)
                 | ((uint)__builtin_bit_cast(unsigned short, l) << 16);
        }
        *reinterpret_cast<uint4*>(&xbuf[buf][rs * XSTR + c4 * 4]) =
            make_uint4(p[0], p[1], p[2], p[3]);
    };
    auto compute = [&](int buf, const half8* wv) {
        #pragma unroll
        for (int s = 0; s < 2; s++) {
            const uint* rp = &xbuf[buf][(tau * 16 + c) * XSTR + s * 32 + quad * 8];
            uint u8[8];
            *reinterpret_cast<uint4*>(u8)     = *reinterpret_cast<const uint4*>(rp);
            *reinterpret_cast<uint4*>(u8 + 4) = *reinterpret_cast<const uint4*>(rp + 4);
            uint hh[4], ll[4];
            #pragma unroll
            for (int q = 0; q < 4; q++) {
                hh[q] = (u8[2 * q] & 0xffffu) | (u8[2 * q + 1] << 16);
                ll[q] = (u8[2 * q] >> 16) | (u8[2 * q + 1] & 0xffff0000u);
            }
            const half8 ah = __builtin_bit_cast(half8, make_uint4(hh[0], hh[1], hh[2], hh[3]));
            const half8 al = __builtin_bit_cast(half8, make_uint4(ll[0], ll[1], ll[2], ll[3]));
            accm = __builtin_amdgcn_mfma_f32_16x16x32_f16(ah, wv[2 * s],     accm, 0, 0, 0);
            accl = __builtin_amdgcn_mfma_f32_16x16x32_f16(al, wv[2 * s],     accl, 0, 0, 0);
            accl = __builtin_amdgcn_mfma_f32_16x16x32_f16(ah, wv[2 * s + 1], accl, 0, 0, 0);
        }
    };
    // LDS-publish barrier WITHOUT vmcnt drain: global prefetches stay in
    // flight across it (ds ops complete per lgkmcnt(0); s_barrier orders).
    auto barrier_lds = [&]() {
        asm volatile("s_waitcnt lgkmcnt(0)" ::: "memory");
        __builtin_amdgcn_s_barrier();
        asm volatile("" ::: "memory");
    };

    float4 q0, q1, q2, q3;
    half8 WA[4], WB[4];

    // prologue: chunks 0..3 in flight; buf0 <- chunk0; chunk4 in flight; W(0).
    q0 = xload(0); q1 = xload(1); q2 = xload(2); q3 = xload(3);
    loadWc(0, WA);
    stage(0, q0);            // vmcnt-waits q0 only
    q0 = xload(4);

    #pragma unroll 1
    for (int n = 0; n < NCH; n += 4) {
        loadWc(n + 1, WB);               // issue BEFORE barrier: L2 latency hidden
        barrier_lds();                   // publish buf0 (chunk n)
        compute(0, WA);
        stage(1, q1);  q1 = xload(n + 5);
        loadWc(n + 2, WA);
        barrier_lds();                   // publish buf1 (chunk n+1)
        compute(1, WB);
        stage(0, q2);  q2 = xload(n + 6);
        loadWc(n + 3, WB);
        barrier_lds();                   // publish buf0 (chunk n+2)
        compute(0, WA);
        stage(1, q3);  q3 = xload(n + 7);
        loadWc(n + 4, WA);
        barrier_lds();                   // publish buf1 (chunk n+3)
        compute(1, WB);
        if (n + 4 < NCH) { stage(0, q0); q0 = xload(n + 8); }
    }

    // ---- epilogue: gather 32x64 logits, softmax, top-2 (waves 0-1) ----
    __syncthreads();
    float* red = reinterpret_cast<float*>(&xbuf[0][0]);   // red[row*65 + expert]
    const float scale = 1.0f / 2048.0f;
    #pragma unroll
    for (int i = 0; i < 4; i++)
        red[(tau * 16 + quad * 4 + i) * 65 + et * 16 + c] = accm[i] + accl[i] * scale;
    __syncthreads();

    if (wave >= 2) return;

    float bvt[4];
    #pragma unroll
    for (int t = 0; t < 4; t++) bvt[t] = bias[c + 16 * t];

    #pragma unroll
    for (int i = 0; i < 4; i++) {
        const int row = wave * 16 + quad * 4 + i;
        float lt[4];
        #pragma unroll
        for (int t = 0; t < 4; t++)
            lt[t] = red[row * 65 + 16 * t + c] + bvt[t];
        const float l0 = lt[0], l1 = lt[1], l2 = lt[2], l3 = lt[3];

        float m = fmaxf(fmaxf(l0, l1), fmaxf(l2, l3));
        #pragma unroll
        for (int off = 1; off < 16; off <<= 1)
            m = fmaxf(m, __shfl_xor(m, off, 64));

        const float e0 = expf(l0 - m), e1 = expf(l1 - m);
        const float e2 = expf(l2 - m), e3 = expf(l3 - m);
        float s = e0 + e1 + e2 + e3;
        #pragma unroll
        for (int off = 1; off < 16; off <<= 1)
            s += __shfl_xor(s, off, 64);

        const float p0 = e0 / s, p1 = e1 / s, p2 = e2 / s, p3 = e3 / s;

        // keys: (prob bits << 32) | (63 - expert); experts c, c+16, c+32, c+48
        const unsigned long long ka =
            ((unsigned long long)__float_as_uint(p0) << 32) | (unsigned long long)(63 - c);
        const unsigned long long kb_ =
            ((unsigned long long)__float_as_uint(p1) << 32) | (unsigned long long)(47 - c);
        const unsigned long long kc_ =
            ((unsigned long long)__float_as_uint(p2) << 32) | (unsigned long long)(31 - c);
        const unsigned long long kd =
            ((unsigned long long)__float_as_uint(p3) << 32) | (unsigned long long)(15 - c);

        unsigned long long hi1 = ka > kb_ ? ka : kb_, lo1 = ka > kb_ ? kb_ : ka;
        unsigned long long hi2 = kc_ > kd ? kc_ : kd, lo2 = kc_ > kd ? kd : kc_;
        unsigned long long k1 = hi1 > hi2 ? hi1 : hi2;
        unsigned long long mn = hi1 > hi2 ? hi2 : hi1;
        unsigned long long mx = lo1 > lo2 ? lo1 : lo2;
        unsigned long long k2 = mn > mx ? mn : mx;

        #pragma unroll
        for (int off = 1; off < 16; off <<= 1) {
            const unsigned long long o1 = __shfl_xor(k1, off, 64);
            const unsigned long long o2 = __shfl_xor(k2, off, 64);
            const unsigned long long n1 = k1 > o1 ? k1 : o1;
            const unsigned long long w1 = k1 > o1 ? o1 : k1;   // loser of firsts
            const unsigned long long w2 = k2 > o2 ? k2 : o2;   // best of seconds
            k1 = n1;
            k2 = w1 > w2 ? w1 : w2;
        }

        if (c == 0) {
            const int gr = r0 + row;
            out[gr * 2 + 0] = (float)(63 - (int)(k1 & 0xFFFFFFFFull));
            out[gr * 2 + 1] = (float)(63 - (int)(k2 & 0xFFFFFFFFull));
            out[M_DIM * 2 + gr * 2 + 0] = __uint_as_float((unsigned)(k1 >> 32));
            out[M_DIM * 2 + gr * 2 + 1] = __uint_as_float((unsigned)(k2 >> 32));
        }
    }
}

extern "C" void kernel_launch(void* const* d_in, const int* in_sizes, int n_in,
                              void* d_out, int out_size, void* d_ws, size_t ws_size,
                              hipStream_t stream) {
    const float* x  = (const float*)d_in[0];
    const float* Wm = (const float*)d_in[1];
    const float* b  = (const float*)d_in[2];
    float* out = (float*)d_out;
    _Float16* wsT = (_Float16*)d_ws;   // 64*4*2*512*2 B = 512 KB

    split_w_kernel<<<dim3(64), dim3(256), 0, stream>>>(Wm, wsT);
    router_mfma_kernel<<<dim3(M_DIM / RM), dim3(512), 0, stream>>>(x, wsT, b, out);
}

// Round 6
// 203.786 us; speedup vs baseline: 1.0345x; 1.0293x over previous
//
#include <hip/hip_runtime.h>
#include <math.h>

// TopKRouter: logits = x(16384x2048) @ W(2048x64) + b; softmax E=64; top-2.
// Output: d_out[0:32768] = indices (as float), d_out[32768:65536] = probs.
//
// R5: revert to R0's barrier-free per-wave-private structure (202.6 us; the
// cooperative-barrier restructures R3/R4 both lost ~8 us to lockstep). Attack
// the VALU pipe instead (static mix: VALU ~2x MFMA cycles at 2 waves/SIMD):
//  (a) split-plane LDS: h-plane (row uints 0..31) and l-plane (32..63) stored
//      separately -> step() reads ah/al as direct ds_read_b128, the 16-op/step
//      hi/lo repack is GONE (ds_read count unchanged).
//  (b) conversion via mask + v_cvt_pkrtz: h = v & 0xFFFFE000 (exact fp16 RTZ
//      value, 1 op), l = (v-h)*2048 (2 ops), one pkrtz per packed pair ->
//      4 VALU/elem vs ~7 (pkrtz of masked h is exact; residual <=2^-11 rel,
//      captured by l at 2^-21 — negligible vs shared 2^-11 W-lo term).
//  (c) staging re-tiled to 8-k-octets/thread so h/l writes remain full
//      ds_write_b128 (8/chunk, same as R0); x loads 2x float4 per row-group.
// Main-loop schedule, W path, epilogue: byte-identical to R0.

#define D_DIM 2048
#define E_DIM 64
#define M_DIM 16384
#define RM 32             // rows per block
#define BKC 64            // k per chunk
#define NCHW 8            // chunks per wave (512/64)
#define XSTR 68           // padded LDS row stride in uints (h:0-31, l:32-63, pad)

typedef _Float16 half8 __attribute__((ext_vector_type(8)));
typedef float floatx4 __attribute__((ext_vector_type(4)));
typedef unsigned int uint;

// ---------------- kernel 1: W split into fragment-linear layout (unchanged) ----
// For k-step g (32 k), tile t, plane p (0=hi,1=lo):
//   wsT[((g*4+t)*2+p)*512 + lane*8 + j] = plane(W[g*32 + quad*8 + j][16t + c]),
//   lane = quad*16 + c.
__global__ __launch_bounds__(256) void split_w_kernel(
    const float* __restrict__ Wm, _Float16* __restrict__ wsT)
{
    const int tid = threadIdx.x;
    const int n   = tid & 63;
    const int kk0 = tid >> 6;           // 0..3
    const int g   = blockIdx.x;         // 0..63
    #pragma unroll
    for (int r = 0; r < 8; r++) {
        const int kk = kk0 + r * 4;     // 0..31
        const float v = Wm[(size_t)(g * 32 + kk) * E_DIM + n];
        const _Float16 h = (_Float16)v;
        const _Float16 l = (_Float16)((v - (float)h) * 2048.0f);
        const int t = n >> 4, cc = n & 15, qd = kk >> 3, j = kk & 7;
        const size_t base = (size_t)((g * 4 + t) * 2) * 512 + (size_t)(qd * 16 + cc) * 8 + j;
        wsT[base]       = h;
        wsT[base + 512] = l;
    }
}

// ---------------- kernel 2: LDS-staged MFMA GEMM + softmax + top-2 ----------------
__global__ __launch_bounds__(256, 2) void router_mfma_kernel(
    const float* __restrict__ x, const _Float16* __restrict__ wsT,
    const float* __restrict__ bias, float* __restrict__ out)
{
    __shared__ uint xbuf[4][2][RM * XSTR];   // [wave][buf][row*XSTR + u]  (69632 B)

    const int lane = threadIdx.x & 63;
    const int wave = threadIdx.x >> 6;
    const int c    = lane & 15;
    const int quad = lane >> 4;
    const int c8   = lane & 7;               // staging k-octet 0..7
    const int rq   = lane >> 3;              // staging row-in-group 0..7
    const int r0   = blockIdx.x * RM;
    const int kb   = wave * (D_DIM / 4);     // 512 per wave

    // staging source: iter i covers row i*8+rq, k = c8*8 .. +7 (+chunk*BKC)
    const float* xg = x + (size_t)(r0 + rq) * D_DIM + kb + c8 * 8;
    const _Float16* wbase = wsT + (size_t)(wave * 16) * 4096 + lane * 8;

    floatx4 accm[2][4] = {};
    floatx4 accl[2][4] = {};
    float4 xa[8], xb[8];
    half8 wh0[4], wl0[4], wh1[4], wl1[4];

    auto loadx = [&](int n, float4* dst) {
        const int nn = n < NCHW ? n : NCHW - 1;
        #pragma unroll
        for (int i = 0; i < 4; i++) {
            const float* p = xg + (size_t)i * 8 * D_DIM + nn * BKC;
            dst[2 * i]     = *reinterpret_cast<const float4*>(p);
            dst[2 * i + 1] = *reinterpret_cast<const float4*>(p + 4);
        }
    };
    auto stage = [&](int buf, const float4* src) {
        uint* dst = &xbuf[wave][buf][0];
        #pragma unroll
        for (int i = 0; i < 4; i++) {
            const int row = i * 8 + rq;
            const float f[8] = {src[2 * i].x,     src[2 * i].y,     src[2 * i].z,     src[2 * i].w,
                                src[2 * i + 1].x, src[2 * i + 1].y, src[2 * i + 1].z, src[2 * i + 1].w};
            uint hq[4], lq[4];
            #pragma unroll
            for (int p = 0; p < 4; p++) {
                const float f0 = f[2 * p], f1 = f[2 * p + 1];
                const float h0 = __uint_as_float(__float_as_uint(f0) & 0xFFFFE000u);
                const float h1 = __uint_as_float(__float_as_uint(f1) & 0xFFFFE000u);
                const float l0 = (f0 - h0) * 2048.0f;
                const float l1 = (f1 - h1) * 2048.0f;
                hq[p] = __builtin_bit_cast(uint, __builtin_amdgcn_cvt_pkrtz(h0, h1));
                lq[p] = __builtin_bit_cast(uint, __builtin_amdgcn_cvt_pkrtz(l0, l1));
            }
            *reinterpret_cast<uint4*>(dst + row * XSTR + c8 * 4) =
                make_uint4(hq[0], hq[1], hq[2], hq[3]);
            *reinterpret_cast<uint4*>(dst + row * XSTR + 32 + c8 * 4) =
                make_uint4(lq[0], lq[1], lq[2], lq[3]);
        }
    };
    auto loadW = [&](int u, half8* wh, half8* wl) {   // u = local k-step 0..15
        const int uu = u < 16 ? u : 15;
        const _Float16* p = wbase + (size_t)uu * 4096;
        #pragma unroll
        for (int t = 0; t < 4; t++) {
            wh[t] = *reinterpret_cast<const half8*>(p + t * 1024);
            wl[t] = *reinterpret_cast<const half8*>(p + t * 1024 + 512);
        }
    };
    auto step = [&](int buf, int s, const half8* wh, const half8* wl) {
        #pragma unroll
        for (int tau = 0; tau < 2; tau++) {
            // k = s*32 + quad*8 + 0..7  ->  uint pairs at s*16 + quad*4 .. +3
            const uint* rp = &xbuf[wave][buf][(tau * 16 + c) * XSTR + s * 16 + quad * 4];
            const uint4 hu = *reinterpret_cast<const uint4*>(rp);
            const uint4 lu = *reinterpret_cast<const uint4*>(rp + 32);
            const half8 ah = __builtin_bit_cast(half8, hu);
            const half8 al = __builtin_bit_cast(half8, lu);
            #pragma unroll
            for (int t = 0; t < 4; t++) {
                accm[tau][t] = __builtin_amdgcn_mfma_f32_16x16x32_f16(ah, wh[t], accm[tau][t], 0, 0, 0);
                accl[tau][t] = __builtin_amdgcn_mfma_f32_16x16x32_f16(al, wh[t], accl[tau][t], 0, 0, 0);
                accl[tau][t] = __builtin_amdgcn_mfma_f32_16x16x32_f16(ah, wl[t], accl[tau][t], 0, 0, 0);
            }
        }
    };

    // prologue
    loadx(0, xa);
    loadx(1, xb);
    loadW(0, wh0, wl0);
    stage(0, xa);

    #pragma unroll 1
    for (int n = 0; n < NCHW; n += 2) {
        loadx(n + 2, xa);
        loadW(2 * n + 1, wh1, wl1);
        stage(1, xb);                      // chunk n+1 -> buf1
        step(0, 0, wh0, wl0);              // chunk n, s=0
        loadW(2 * n + 2, wh0, wl0);
        step(0, 1, wh1, wl1);              // chunk n, s=1
        loadx(n + 3, xb);
        loadW(2 * n + 3, wh1, wl1);
        if (n + 2 < NCHW) stage(0, xa);    // chunk n+2 -> buf0
        step(1, 0, wh0, wl0);              // chunk n+1, s=0
        loadW(2 * n + 4, wh0, wl0);
        step(1, 1, wh1, wl1);              // chunk n+1, s=1
    }

    // ---- cross-wave reduction (red aliases xbuf after barrier) ----
    __syncthreads();
    float* red = reinterpret_cast<float*>(&xbuf[0][0][0]);   // red[(w*32+row)*65 + col]
    const float scale = 1.0f / 2048.0f;
    #pragma unroll
    for (int tau = 0; tau < 2; tau++)
        #pragma unroll
        for (int t = 0; t < 4; t++)
            #pragma unroll
            for (int i = 0; i < 4; i++)
                red[(wave * 32 + tau * 16 + quad * 4 + i) * 65 + c + 16 * t] =
                    accm[tau][t][i] + accl[tau][t][i] * scale;
    __syncthreads();

    if (wave >= 2) return;

    float bvt[4];
    #pragma unroll
    for (int t = 0; t < 4; t++) bvt[t] = bias[c + 16 * t];

    #pragma unroll
    for (int i = 0; i < 4; i++) {
        const int row = wave * 16 + quad * 4 + i;
        float lt[4];
        #pragma unroll
        for (int t = 0; t < 4; t++) {
            const int col = c + 16 * t;
            lt[t] = red[(0 * 32 + row) * 65 + col] + red[(1 * 32 + row) * 65 + col]
                  + red[(2 * 32 + row) * 65 + col] + red[(3 * 32 + row) * 65 + col] + bvt[t];
        }
        const float l0 = lt[0], l1 = lt[1], l2 = lt[2], l3 = lt[3];

        float m = fmaxf(fmaxf(l0, l1), fmaxf(l2, l3));
        #pragma unroll
        for (int off = 1; off < 16; off <<= 1)
            m = fmaxf(m, __shfl_xor(m, off, 64));

        const float e0 = expf(l0 - m), e1 = expf(l1 - m);
        const float e2 = expf(l2 - m), e3 = expf(l3 - m);
        float s = e0 + e1 + e2 + e3;
        #pragma unroll
        for (int off = 1; off < 16; off <<= 1)
            s += __shfl_xor(s, off, 64);

        const float p0 = e0 / s, p1 = e1 / s, p2 = e2 / s, p3 = e3 / s;

        // keys: (prob bits << 32) | (63 - expert); experts c, c+16, c+32, c+48
        const unsigned long long ka =
            ((unsigned long long)__float_as_uint(p0) << 32) | (unsigned long long)(63 - c);
        const unsigned long long kb_ =
            ((unsigned long long)__float_as_uint(p1) << 32) | (unsigned long long)(47 - c);
        const unsigned long long kc_ =
            ((unsigned long long)__float_as_uint(p2) << 32) | (unsigned long long)(31 - c);
        const unsigned long long kd =
            ((unsigned long long)__float_as_uint(p3) << 32) | (unsigned long long)(15 - c);

        unsigned long long hi1 = ka > kb_ ? ka : kb_, lo1 = ka > kb_ ? kb_ : ka;
        unsigned long long hi2 = kc_ > kd ? kc_ : kd, lo2 = kc_ > kd ? kd : kc_;
        unsigned long long k1 = hi1 > hi2 ? hi1 : hi2;
        unsigned long long mn = hi1 > hi2 ? hi2 : hi1;
        unsigned long long mx = lo1 > lo2 ? lo1 : lo2;
        unsigned long long k2 = mn > mx ? mn : mx;

        #pragma unroll
        for (int off = 1; off < 16; off <<= 1) {
            const unsigned long long o1 = __shfl_xor(k1, off, 64);
            const unsigned long long o2 = __shfl_xor(k2, off, 64);
            const unsigned long long n1 = k1 > o1 ? k1 : o1;
            const unsigned long long w1 = k1 > o1 ? o1 : k1;   // loser of firsts
            const unsigned long long w2 = k2 > o2 ? k2 : o2;   // best of seconds
            k1 = n1;
            k2 = w1 > w2 ? w1 : w2;
        }

        if (c == 0) {
            const int gr = r0 + row;
            out[gr * 2 + 0] = (float)(63 - (int)(k1 & 0xFFFFFFFFull));
            out[gr * 2 + 1] = (float)(63 - (int)(k2 & 0xFFFFFFFFull));
            out[M_DIM * 2 + gr * 2 + 0] = __uint_as_float((unsigned)(k1 >> 32));
            out[M_DIM * 2 + gr * 2 + 1] = __uint_as_float((unsigned)(k2 >> 32));
        }
    }
}

extern "C" void kernel_launch(void* const* d_in, const int* in_sizes, int n_in,
                              void* d_out, int out_size, void* d_ws, size_t ws_size,
                              hipStream_t stream) {
    const float* x  = (const float*)d_in[0];
    const float* Wm = (const float*)d_in[1];
    const float* b  = (const float*)d_in[2];
    float* out = (float*)d_out;
    _Float16* wsT = (_Float16*)d_ws;   // 64*4*2*512*2 B = 512 KB

    split_w_kernel<<<dim3(64), dim3(256), 0, stream>>>(Wm, wsT);
    router_mfma_kernel<<<dim3(M_DIM / RM), dim3(256), 0, stream>>>(x, wsT, b, out);
}